// Round 3
// baseline (85.374 us; speedup 1.0000x reference)
//
#include <hip/hip_runtime.h>
#include <math.h>

#define BB 16
#define PP 4096
#define TT 1024
#define JT 8
#define SENT 0xFFFFFFFFu

// Grid: 512 blocks = 16 b x 32 target-tiles. Block = 256 thr = 4 waves.
// Each wave owns 8 targets, scans all P preds (lane = p mod 64, 64 preds/lane).
// Writes best[b*TT+t] = argmin-d2 valid pred index, or SENT. Every slot written
// -> no zero-init of workspace needed.
__global__ __launch_bounds__(256) void match_kernel(const float* __restrict__ pred,
                                                    const float* __restrict__ gt,
                                                    unsigned int* __restrict__ best) {
    const int blk   = blockIdx.x;
    const int b     = blk >> 5;          // 32 blocks per batch
    const int ttile = blk & 31;          // 32 targets per block
    const int wave  = threadIdx.x >> 6;  // 0..3
    const int lane  = threadIdx.x & 63;
    const int tbase = ttile * 32 + wave * JT;

    const float* gb = gt + ((size_t)(b * TT + tbase)) * 3;
    float gc[JT], gx[JT], gy[JT], bd[JT];
    unsigned int bp[JT];
    #pragma unroll
    for (int j = 0; j < JT; ++j) {
        gc[j] = gb[j * 3 + 0];
        gx[j] = gb[j * 3 + 1];
        gy[j] = gb[j * 3 + 2];
        bd[j] = INFINITY;
        bp[j] = SENT;
    }

    const float* pl = pred + (size_t)b * PP * 3 + lane * 3;

    #pragma unroll 2
    for (int i = 0; i < PP / 64; ++i) {
        const float pc = pl[0];
        const float px = pl[1];
        const float py = pl[2];
        pl += 64 * 3;
        const unsigned int p = (unsigned int)(lane + (i << 6));
        #pragma unroll
        for (int j = 0; j < JT; ++j) {
            const float dx = px - gx[j];
            const float dy = py - gy[j];
            const float d2 = fmaf(dx, dx, dy * dy);
            // valid: class match AND dist<=5 (d2<=25); strict < keeps lowest p in-lane
            const bool ok = (pc == gc[j]) & (d2 <= 25.0f) & (d2 < bd[j]);
            if (ok) { bd[j] = d2; bp[j] = p; }
        }
    }

    // pack: d2 >= 0 so float-bit order == uint order; lower p wins ties
    unsigned long long key[JT];
    #pragma unroll
    for (int j = 0; j < JT; ++j)
        key[j] = ((unsigned long long)__float_as_uint(bd[j]) << 32) | bp[j];

    for (int off = 32; off; off >>= 1) {
        #pragma unroll
        for (int j = 0; j < JT; ++j) {
            const unsigned long long o = __shfl_down(key[j], off, 64);
            if (o < key[j]) key[j] = o;
        }
    }

    if (lane == 0) {
        #pragma unroll
        for (int j = 0; j < JT; ++j)
            best[b * TT + tbase + j] = (unsigned int)key[j];
    }
}

// Single block: scatter 16K best-indices into an 8KB LDS bitmap (B*P bits),
// popcount -> tp, compute F1 loss scalar.
__global__ __launch_bounds__(1024) void count_kernel(const unsigned int* __restrict__ best,
                                                     float* __restrict__ out) {
    __shared__ unsigned int bm[BB * PP / 32];   // 2048 words
    for (int i = threadIdx.x; i < BB * PP / 32; i += 1024) bm[i] = 0;
    __syncthreads();

    const uint4* b4 = (const uint4*)best;
    for (int i = threadIdx.x; i < (BB * TT / 4); i += 1024) {
        const uint4 v = b4[i];
        const int t0 = i * 4;  // global target index b*TT + t
        const unsigned int vs[4] = {v.x, v.y, v.z, v.w};
        #pragma unroll
        for (int k = 0; k < 4; ++k) {
            if (vs[k] != SENT) {
                const unsigned int g = (unsigned int)((t0 + k) >> 10) * PP + vs[k];
                atomicOr(&bm[g >> 5], 1u << (g & 31));
            }
        }
    }
    __syncthreads();

    int sum = 0;
    for (int i = threadIdx.x; i < BB * PP / 32; i += 1024) sum += __popc(bm[i]);
    for (int off = 32; off; off >>= 1) sum += __shfl_down(sum, off, 64);

    __shared__ int ss[16];
    const int wid  = threadIdx.x >> 6;
    const int lane = threadIdx.x & 63;
    if (lane == 0) ss[wid] = sum;
    __syncthreads();
    if (threadIdx.x == 0) {
        int tp_i = 0;
        for (int w = 0; w < 16; ++w) tp_i += ss[w];
        const float tp = (float)tp_i;
        const float eps = 1e-6f;
        const float fp = (float)(BB * PP) - tp;
        const float fn = (float)(BB * TT) - tp;
        const float precision = (tp + eps) / (tp + eps + fp + eps);
        const float recall    = (tp + eps) / (tp + fn + eps);
        const float f1 = 2.0f * precision * recall / (precision + recall);
        out[0] = 1.0f - f1;
    }
}

extern "C" void kernel_launch(void* const* d_in, const int* in_sizes, int n_in,
                              void* d_out, int out_size, void* d_ws, size_t ws_size,
                              hipStream_t stream) {
    const float* pred = (const float*)d_in[0];  // (B, P, 3): cls, x, y
    const float* gt   = (const float*)d_in[1];  // (B, T, 3)
    float* out = (float*)d_out;
    unsigned int* best = (unsigned int*)d_ws;   // B*T u32 = 64 KB

    match_kernel<<<BB * TT / 32, 256, 0, stream>>>(pred, gt, best);
    count_kernel<<<1, 1024, 0, stream>>>(best, out);
}

// Round 4
// 76.077 us; speedup vs baseline: 1.1222x; 1.1222x over previous
//
#include <hip/hip_runtime.h>
#include <math.h>

#define BB 16
#define PP 4096
#define TT 1024
#define JT 8
#define HALF 2048   // preds per block (P split in 2 for occupancy)
#define SENT 0xFFFFFFFFu

// Grid: 1024 blocks = 16 b x 32 target-tiles x 2 P-halves. Block = 256 thr = 4 waves.
// Each wave owns 8 targets, scans its P-half (lane = p mod 64). Radius test is
// DEFERRED: track argmin d2 over class-matched preds only; min(d2)<=25 checked in
// count_kernel (identical outcome to masking per-pair). Writes packed u64 key
// (d2_bits<<32 | p) per (target, half) -> every slot written, no ws zero-init.
__global__ __launch_bounds__(256) void match_kernel(const float* __restrict__ pred,
                                                    const float* __restrict__ gt,
                                                    unsigned long long* __restrict__ part) {
    const int blk   = blockIdx.x;
    const int b     = blk >> 6;          // 64 blocks per batch
    const int ttile = (blk >> 1) & 31;   // 32 targets per block
    const int half  = blk & 1;
    const int wave  = threadIdx.x >> 6;  // 0..3
    const int lane  = threadIdx.x & 63;
    const int tbase = ttile * 32 + wave * JT;

    const float* gb = gt + ((size_t)(b * TT + tbase)) * 3;
    float gc[JT], gx[JT], gy[JT], bd[JT];
    unsigned int bp[JT];
    #pragma unroll
    for (int j = 0; j < JT; ++j) {
        gc[j] = gb[j * 3 + 0];
        gx[j] = gb[j * 3 + 1];
        gy[j] = gb[j * 3 + 2];
        bd[j] = INFINITY;
        bp[j] = SENT;
    }

    const int pbase = half * HALF;
    const float* pl = pred + (size_t)b * PP * 3 + (size_t)(pbase + lane) * 3;

    // depth-1 software pipeline: next triple loads while current computes
    float c0 = pl[0], x0 = pl[1], y0 = pl[2];
    #pragma unroll 4
    for (int i = 0; i < HALF / 64 - 1; ++i) {
        pl += 192;
        const float c1 = pl[0], x1 = pl[1], y1 = pl[2];
        const unsigned int p = (unsigned int)(pbase + (i << 6) + lane);
        #pragma unroll
        for (int j = 0; j < JT; ++j) {
            const float dx = x0 - gx[j];
            const float dy = y0 - gy[j];
            const float d2 = fmaf(dx, dx, dy * dy);
            const bool ok = (c0 == gc[j]) & (d2 < bd[j]);
            if (ok) { bd[j] = d2; bp[j] = p; }
        }
        c0 = c1; x0 = x1; y0 = y1;
    }
    {   // epilogue iteration
        const unsigned int p = (unsigned int)(pbase + HALF - 64 + lane);
        #pragma unroll
        for (int j = 0; j < JT; ++j) {
            const float dx = x0 - gx[j];
            const float dy = y0 - gy[j];
            const float d2 = fmaf(dx, dx, dy * dy);
            const bool ok = (c0 == gc[j]) & (d2 < bd[j]);
            if (ok) { bd[j] = d2; bp[j] = p; }
        }
    }

    // pack: d2 >= 0 so float-bit order == uint order; lower p wins ties
    unsigned long long key[JT];
    #pragma unroll
    for (int j = 0; j < JT; ++j)
        key[j] = ((unsigned long long)__float_as_uint(bd[j]) << 32) | bp[j];

    for (int off = 32; off; off >>= 1) {
        #pragma unroll
        for (int j = 0; j < JT; ++j) {
            const unsigned long long o = __shfl_down(key[j], off, 64);
            if (o < key[j]) key[j] = o;
        }
    }

    if (lane == 0) {
        #pragma unroll
        for (int j = 0; j < JT; ++j)
            part[(size_t)half * (BB * TT) + b * TT + tbase + j] = key[j];
    }
}

// Single block: combine the 2 P-halves per target, apply deferred radius test,
// scatter hit preds into an 8KB LDS bitmap, popcount -> tp, F1 scalar.
__global__ __launch_bounds__(1024) void count_kernel(const unsigned long long* __restrict__ part,
                                                     float* __restrict__ out) {
    __shared__ unsigned int bm[BB * PP / 32];   // 2048 words
    for (int i = threadIdx.x; i < BB * PP / 32; i += 1024) bm[i] = 0;
    __syncthreads();

    const unsigned int lim = __float_as_uint(25.0f);   // d2 <= 25  <=>  dist <= 5
    for (int i = threadIdx.x; i < BB * TT; i += 1024) {
        unsigned long long k0 = part[i];
        unsigned long long k1 = part[(size_t)(BB * TT) + i];
        const unsigned long long k = k0 < k1 ? k0 : k1;
        if ((unsigned int)(k >> 32) <= lim) {
            const unsigned int g = (unsigned int)(i >> 10) * PP + (unsigned int)k;
            atomicOr(&bm[g >> 5], 1u << (g & 31));
        }
    }
    __syncthreads();

    int sum = 0;
    for (int i = threadIdx.x; i < BB * PP / 32; i += 1024) sum += __popc(bm[i]);
    for (int off = 32; off; off >>= 1) sum += __shfl_down(sum, off, 64);

    __shared__ int ss[16];
    const int wid  = threadIdx.x >> 6;
    const int lane = threadIdx.x & 63;
    if (lane == 0) ss[wid] = sum;
    __syncthreads();
    if (threadIdx.x == 0) {
        int tp_i = 0;
        for (int w = 0; w < 16; ++w) tp_i += ss[w];
        const float tp = (float)tp_i;
        const float eps = 1e-6f;
        const float fp = (float)(BB * PP) - tp;
        const float fn = (float)(BB * TT) - tp;
        const float precision = (tp + eps) / (tp + eps + fp + eps);
        const float recall    = (tp + eps) / (tp + fn + eps);
        const float f1 = 2.0f * precision * recall / (precision + recall);
        out[0] = 1.0f - f1;
    }
}

extern "C" void kernel_launch(void* const* d_in, const int* in_sizes, int n_in,
                              void* d_out, int out_size, void* d_ws, size_t ws_size,
                              hipStream_t stream) {
    const float* pred = (const float*)d_in[0];  // (B, P, 3): cls, x, y
    const float* gt   = (const float*)d_in[1];  // (B, T, 3)
    float* out = (float*)d_out;
    unsigned long long* part = (unsigned long long*)d_ws;   // 2 * B*T u64 = 256 KB

    match_kernel<<<BB * TT / 32 * 2, 256, 0, stream>>>(pred, gt, part);
    count_kernel<<<1, 1024, 0, stream>>>(part, out);
}